// Round 6
// baseline (372.967 us; speedup 1.0000x reference)
//
#include <hip/hip_runtime.h>

// GNN layer (fp32 in/out):
//   out_i = (e_i@W1^T + b1 + b2) + dinv_i * sum_{j in N(i)} z_j
//   z_j   = dinv_j * (e_j@W1^T + e_j^2@W2^T)
// (refactor of: (e + L e)@W1^T + b1 + (L e^2)@W2^T + b2, L = D^-1/2 A D^-1/2)
// CSR build exploits symmetric edge layout row=[u;it], col=[it;u].
// Learned-on-HW rules: (1) never issue sub-dword global stores (ECC RMW: 1.5 GB
// fetch for 37 MB of ushort stores, r4); (2) never issue scattered plain dword
// stores either — per-XCD L2 dirty-line thrash writes ~64 B/store (130 MB for
// 8 MB payload, r5); scattered writes go through ATOMICS (memory-side coherent
// point coalesces all writes to a line before writeback — k_deg evidence).

__device__ __forceinline__ float bf2f(unsigned short u) {
    union { unsigned int i; float f; } c; c.i = ((unsigned int)u) << 16; return c.f;
}
__device__ __forceinline__ unsigned int f2bf(float f) {
    union { float f; unsigned int i; } c; c.f = f;
    unsigned int r = c.i + 0x7FFFu + ((c.i >> 16) & 1u);  // RTN-even
    return r >> 16;
}

__global__ void k_deg(const int* __restrict__ row, const int* __restrict__ col,
                      int* __restrict__ deg, int Eh) {
    int e0 = (blockIdx.x * blockDim.x + threadIdx.x) * 2;
    if (e0 + 1 < Eh) {
        int2 u = *(const int2*)&row[e0];
        int2 v = *(const int2*)&col[e0];
        atomicAdd(&deg[u.x], 1); atomicAdd(&deg[v.x], 1);
        atomicAdd(&deg[u.y], 1); atomicAdd(&deg[v.y], 1);
    } else if (e0 < Eh) {
        atomicAdd(&deg[row[e0]], 1); atomicAdd(&deg[col[e0]], 1);
    }
}

// Exclusive scan of deg (1024 elems/block)
__global__ void k_scan1(const int* __restrict__ deg, int* __restrict__ part,
                        int* __restrict__ bsums, int n) {
    __shared__ int lds[256];
    int t = threadIdx.x;
    int base = blockIdx.x * 1024 + t * 4;
    int v0 = (base + 0 < n) ? deg[base + 0] : 0;
    int v1 = (base + 1 < n) ? deg[base + 1] : 0;
    int v2 = (base + 2 < n) ? deg[base + 2] : 0;
    int v3 = (base + 3 < n) ? deg[base + 3] : 0;
    int s = v0 + v1 + v2 + v3;
    lds[t] = s;
    __syncthreads();
    for (int off = 1; off < 256; off <<= 1) {
        int x = (t >= off) ? lds[t - off] : 0;
        __syncthreads();
        lds[t] += x;
        __syncthreads();
    }
    int excl = lds[t] - s;
    if (t == 255) bsums[blockIdx.x] = lds[255];
    int run = excl;
    if (base + 0 < n) { part[base + 0] = run; run += v0; }
    if (base + 1 < n) { part[base + 1] = run; run += v1; }
    if (base + 2 < n) { part[base + 2] = run; run += v2; }
    if (base + 3 < n) { part[base + 3] = run; }
}

// parallel exclusive scan of block sums (nblk=141 fits one 256-thread block)
__global__ void k_scan2(int* __restrict__ bsums, int nblk) {
    __shared__ int lds[256];
    int t = threadIdx.x;
    int v = (t < nblk) ? bsums[t] : 0;
    lds[t] = v;
    __syncthreads();
    for (int off = 1; off < 256; off <<= 1) {
        int x = (t >= off) ? lds[t - off] : 0;
        __syncthreads();
        lds[t] += x;
        __syncthreads();
    }
    if (t < nblk) bsums[t] = lds[t] - v;
    __syncthreads();
    if (t == 0 && nblk > 256) {  // defensive fallback, unused at n=144242
        int s = lds[255];
        for (int k = 256; k < nblk; k++) { int tmp = bsums[k]; bsums[k] = s; s += tmp; }
    }
}

// start/cursor, dinv, and interleaved weight buffer
// wBg[k*32+q] = {W1[2q][k], W2[2q][k], W1[2q+1][k], W2[2q+1][k]}
__global__ void k_scan3(const int* __restrict__ part, const int* __restrict__ bsums,
                        const int* __restrict__ deg, float* __restrict__ dinv,
                        int* __restrict__ start, int* __restrict__ cursor,
                        const float* __restrict__ W1, const float* __restrict__ W2,
                        float4* __restrict__ wBg, int n, int E) {
    int i = blockIdx.x * blockDim.x + threadIdx.x;
    if (i < n) {
        int s = part[i] + bsums[i >> 10];
        start[i] = s;
        cursor[i] = s;
        int d = deg[i];
        dinv[i] = d > 0 ? rsqrtf((float)d) : 0.0f;
    }
    if (i == 0) start[n] = E;
    if (i < 2048) {
        int k = i >> 5, q = i & 31;
        wBg[i] = make_float4(W1[(2 * q) * 64 + k], W2[(2 * q) * 64 + k],
                             W1[(2 * q + 1) * 64 + k], W2[(2 * q + 1) * 64 + k]);
    }
}

// CSR fill: scattered payload stores via atomicExch (see header comment).
__global__ void k_fill(const int* __restrict__ row, const int* __restrict__ col,
                       int* __restrict__ cursor, int* __restrict__ scol, int Eh) {
    int e0 = (blockIdx.x * blockDim.x + threadIdx.x) * 2;
    if (e0 + 1 < Eh) {
        int2 u = *(const int2*)&row[e0];
        int2 v = *(const int2*)&col[e0];
        atomicExch(&scol[atomicAdd(&cursor[u.x], 1)], v.x);
        atomicExch(&scol[atomicAdd(&cursor[v.x], 1)], u.x);
        atomicExch(&scol[atomicAdd(&cursor[u.y], 1)], v.y);
        atomicExch(&scol[atomicAdd(&cursor[v.y], 1)], u.y);
    } else if (e0 < Eh) {
        int u = row[e0], v = col[e0];
        atomicExch(&scol[atomicAdd(&cursor[u], 1)], v);
        atomicExch(&scol[atomicAdd(&cursor[v], 1)], u);
    }
}

// Per-node transform: y1p = pack2(e@W1^T + b1 + b2), zp = pack2(dinv*(e@W1^T + e^2@W2^T))
// Half-wave per node: lane q in [0,32) computes output dims 2q, 2q+1; dword stores.
__global__ __launch_bounds__(512, 8) void k_xform(
    const float2* __restrict__ embed2, const float* __restrict__ dinv,
    const float4* __restrict__ wBg, const float* __restrict__ b1,
    const float* __restrict__ b2, unsigned int* __restrict__ y1p,
    unsigned int* __restrict__ zp, int n) {
    __shared__ float4 wB[2048];        // [k*32+q]
    __shared__ float4 ebuf[8][2][32];  // [wave][half][q] = {e2q, e2q^2, e2q+1, e2q+1^2}
    int tid = threadIdx.x;
#pragma unroll
    for (int t = 0; t < 4; t++) wB[tid + 512 * t] = wBg[tid + 512 * t];
    __syncthreads();
    int wave = tid >> 6, lane = tid & 63, half = lane >> 5, q = lane & 31;
    float bs0 = b1[2 * q] + b2[2 * q];
    float bs1 = b1[2 * q + 1] + b2[2 * q + 1];
    for (int ip = blockIdx.x * 16 + wave * 2; ip < n; ip += gridDim.x * 16) {
        int i = ip + half;
        int ic = i < n ? i : n - 1;
        float2 ev = embed2[(size_t)ic * 32 + q];
        ebuf[wave][half][q] = make_float4(ev.x, ev.x * ev.x, ev.y, ev.y * ev.y);
        const float2* eb = (const float2*)&ebuf[wave][half][0];  // [k] = {e_k, e_k^2}
        float y0 = 0.f, s0 = 0.f, y1 = 0.f, s1 = 0.f;
#pragma unroll
        for (int k = 0; k < 64; k++) {
            float4 w = wB[(k << 5) + q];   // b128, consecutive lanes: conflict-free
            float2 ee = eb[k];             // uniform per half-wave: broadcast
            y0 = fmaf(ee.x, w.x, y0);
            s0 = fmaf(ee.y, w.y, s0);
            y1 = fmaf(ee.x, w.z, y1);
            s1 = fmaf(ee.y, w.w, s1);
        }
        if (i < n) {
            float di = dinv[i];
            y1p[(size_t)i * 32 + q] = f2bf(y0 + bs0) | (f2bf(y1 + bs1) << 16);
            zp[(size_t)i * 32 + q] = f2bf(di * (y0 + s0)) | (f2bf(di * (y1 + s1)) << 16);
        }
    }
}

// Pure gather-sum: 16-lane group per node, 4 nodes/wave, no LDS, no syncthreads.
__global__ __launch_bounds__(256, 8) void k_main(
    const ushort4* __restrict__ zb4, const ushort4* __restrict__ y1b4,
    const int* __restrict__ start, const int* __restrict__ scol,
    const float* __restrict__ dinv, float4* __restrict__ out4, int n) {
    int tid = threadIdx.x;
    int wave = tid >> 6, lane = tid & 63, g = lane >> 4, l = lane & 15;
    int i = blockIdx.x * 16 + wave * 4 + g;
    bool valid = i < n;
    int ii = valid ? i : 0;
    int s0 = start[ii];
    int s1 = valid ? start[ii + 1] : s0;

    float4 acc = make_float4(0.f, 0.f, 0.f, 0.f);
    for (int e = s0; e < s1; e += 16) {
        int cnt = s1 - e;
        cnt = cnt > 16 ? 16 : cnt;
        int jv = scol[e + (l < cnt ? l : 0)];
#pragma unroll 8
        for (int k = 0; k < 16; k++) {
            int j = __shfl(jv, (g << 4) + k, 64);
            float m = (k < cnt) ? 1.0f : 0.0f;
            ushort4 z = zb4[(size_t)j * 16 + l];
            acc.x = fmaf(bf2f(z.x), m, acc.x);
            acc.y = fmaf(bf2f(z.y), m, acc.y);
            acc.z = fmaf(bf2f(z.z), m, acc.z);
            acc.w = fmaf(bf2f(z.w), m, acc.w);
        }
    }
    if (valid) {
        float di = dinv[i];
        ushort4 yb = y1b4[(size_t)i * 16 + l];
        float4 o;
        o.x = fmaf(di, acc.x, bf2f(yb.x));
        o.y = fmaf(di, acc.y, bf2f(yb.y));
        o.z = fmaf(di, acc.z, bf2f(yb.z));
        o.w = fmaf(di, acc.w, bf2f(yb.w));
        out4[(size_t)i * 16 + l] = o;
    }
}

extern "C" void kernel_launch(void* const* d_in, const int* in_sizes, int n_in,
                              void* d_out, int out_size, void* d_ws, size_t ws_size,
                              hipStream_t stream) {
    const float* embed = (const float*)d_in[0];
    const int* row = (const int*)d_in[1];
    const int* col = (const int*)d_in[2];
    const float* W1 = (const float*)d_in[3];
    const float* b1 = (const float*)d_in[4];
    const float* W2 = (const float*)d_in[5];
    const float* b2 = (const float*)d_in[6];
    float* out = (float*)d_out;

    int n = in_sizes[0] / 64;   // 144242
    int E = in_sizes[1];        // 2,000,000
    int Eh = E / 2;             // symmetric pairs: row=[u;it], col=[it;u]
    int nblk = (n + 1023) / 1024;
    size_t n64 = (size_t)n * 64;

    char* ws = (char*)d_ws;
    size_t off = 0;
    unsigned int* zp = (unsigned int*)(ws + off);  off += n64 * 2;   // 18.5 MB
    unsigned int* y1p = (unsigned int*)(ws + off); off += n64 * 2;   // 18.5 MB
    float4* wBg = (float4*)(ws + off);             off += 2048 * 16;
    int* scol = (int*)(ws + off);                  off += (size_t)E * 4;
    int* deg = (int*)(ws + off);                   off += (size_t)n * 4;
    float* dinv = (float*)(ws + off);              off += (size_t)n * 4;
    int* part = (int*)(ws + off);                  off += (size_t)n * 4;
    int* bsums = (int*)(ws + off);                 off += (size_t)(nblk + 1) * 4;
    int* start = (int*)(ws + off);                 off += (size_t)(n + 1) * 4;
    int* cursor = (int*)(ws + off);                off += (size_t)n * 4;

    if (off > ws_size) return;  // ws too small -> out stays zero (0.707 absmax signal)

    hipMemsetAsync(deg, 0, (size_t)n * 4, stream);
    int pthreads = (Eh + 1) / 2;
    k_deg<<<(pthreads + 255) / 256, 256, 0, stream>>>(row, col, deg, Eh);
    k_scan1<<<nblk, 256, 0, stream>>>(deg, part, bsums, n);
    k_scan2<<<1, 256, 0, stream>>>(bsums, nblk);
    k_scan3<<<(n + 255) / 256, 256, 0, stream>>>(part, bsums, deg, dinv, start,
                                                 cursor, W1, W2, wBg, n, E);
    k_fill<<<(pthreads + 255) / 256, 256, 0, stream>>>(row, col, cursor, scol, Eh);
    k_xform<<<2048, 512, 0, stream>>>((const float2*)embed, dinv, wBg, b1, b2,
                                      y1p, zp, n);
    k_main<<<(n + 15) / 16, 256, 0, stream>>>((const ushort4*)zp, (const ushort4*)y1p,
                                              start, scol, dinv, (float4*)out, n);
}

// Round 7
// 222.805 us; speedup vs baseline: 1.6740x; 1.6740x over previous
//
#include <hip/hip_runtime.h>

// GNN layer (fp32 in/out):
//   out_i = (e_i@W1^T + b1 + b2) + dinv_i * sum_{j in N(i)} z_j
//   z_j   = dinv_j * (e_j@W1^T + e_j^2@W2^T)
// (refactor of: (e + L e)@W1^T + b1 + (L e^2)@W2^T + b2, L = D^-1/2 A D^-1/2)
// Symmetric edge layout row=[u;it], col=[it;u] -> one pass over 1M pairs.
// HW rules learned here: (r4) sub-dword global stores cause ECC RMW (1.5 GB
// fetch for 37 MB of ushort stores) -> always pack to >=4B. (r5/r6) scattered
// 4B stores AND scattered atomics both write ~64B/line (cross-XCD line
// migration); at 9% BW that's not the wall -- the wall is the DEPENDENT
// atomicAdd->store chain. This round decouples: k_posA (atomics only,
// coalesced pos output) + k_scatterB (independent scattered stores).
// ELL layout (48 slots/node) removes deg/scan/start entirely.

#define SLOTS 48

__device__ __forceinline__ float bf2f(unsigned short u) {
    union { unsigned int i; float f; } c; c.i = ((unsigned int)u) << 16; return c.f;
}
__device__ __forceinline__ unsigned int f2bf(float f) {
    union { float f; unsigned int i; } c; c.f = f;
    unsigned int r = c.i + 0x7FFFu + ((c.i >> 16) & 1u);  // RTN-even
    return r >> 16;
}

__global__ void k_init(int* __restrict__ cursor, int n) {
    int i = blockIdx.x * blockDim.x + threadIdx.x;
    if (i < n) cursor[i] = i * SLOTS;
}

// Pass 1: allocate ELL positions (returning atomics), positions written COALESCED.
__global__ void k_posA(const int* __restrict__ row, const int* __restrict__ col,
                       int* __restrict__ cursor, int* __restrict__ posr,
                       int* __restrict__ posc, int Eh, int nS) {
    int e0 = (blockIdx.x * blockDim.x + threadIdx.x) * 2;
    if (e0 + 1 < Eh) {
        int2 u = *(const int2*)&row[e0];
        int2 v = *(const int2*)&col[e0];
        int2 pu, pv;
        pu.x = atomicAdd(&cursor[u.x], 1);
        pv.x = atomicAdd(&cursor[v.x], 1);
        pu.y = atomicAdd(&cursor[u.y], 1);
        pv.y = atomicAdd(&cursor[v.y], 1);
        pu.x = (pu.x < u.x * SLOTS + SLOTS) ? pu.x : nS;  // overflow -> dump slot
        pv.x = (pv.x < v.x * SLOTS + SLOTS) ? pv.x : nS;
        pu.y = (pu.y < u.y * SLOTS + SLOTS) ? pu.y : nS;
        pv.y = (pv.y < v.y * SLOTS + SLOTS) ? pv.y : nS;
        *(int2*)&posr[e0] = pu;
        *(int2*)&posc[e0] = pv;
    } else if (e0 < Eh) {
        int u = row[e0], v = col[e0];
        int p = atomicAdd(&cursor[u], 1);
        int q = atomicAdd(&cursor[v], 1);
        posr[e0] = (p < u * SLOTS + SLOTS) ? p : nS;
        posc[e0] = (q < v * SLOTS + SLOTS) ? q : nS;
    }
}

// dinv from cursor-end + interleaved weight buffer
// wBg[k*32+q] = {W1[2q][k], W2[2q][k], W1[2q+1][k], W2[2q+1][k]}
__global__ void k_prep(const int* __restrict__ cursor, float* __restrict__ dinv,
                       const float* __restrict__ W1, const float* __restrict__ W2,
                       float4* __restrict__ wBg, int n) {
    int i = blockIdx.x * blockDim.x + threadIdx.x;
    if (i < n) {
        int d = cursor[i] - i * SLOTS;   // true degree (clamp only affected stores)
        dinv[i] = d > 0 ? rsqrtf((float)d) : 0.0f;
    }
    if (i < 2048) {
        int k = i >> 5, q = i & 31;
        wBg[i] = make_float4(W1[(2 * q) * 64 + k], W2[(2 * q) * 64 + k],
                             W1[(2 * q + 1) * 64 + k], W2[(2 * q + 1) * 64 + k]);
    }
}

// Pass 2: scatter neighbor ids to ELL slots. 8 INDEPENDENT stores/thread.
__global__ void k_scatterB(const int* __restrict__ row, const int* __restrict__ col,
                           const int* __restrict__ posr, const int* __restrict__ posc,
                           int* __restrict__ scol, int Eh) {
    int e0 = (blockIdx.x * blockDim.x + threadIdx.x) * 4;
    if (e0 + 3 < Eh) {
        int4 c = *(const int4*)&col[e0];
        int4 p = *(const int4*)&posr[e0];
        int4 r = *(const int4*)&row[e0];
        int4 q = *(const int4*)&posc[e0];
        scol[p.x] = c.x; scol[p.y] = c.y; scol[p.z] = c.z; scol[p.w] = c.w;
        scol[q.x] = r.x; scol[q.y] = r.y; scol[q.z] = r.z; scol[q.w] = r.w;
    } else {
        for (int e = e0; e < Eh; e++) {
            scol[posr[e]] = col[e];
            scol[posc[e]] = row[e];
        }
    }
}

// Per-node transform: y1p = pack2(e@W1^T + b1 + b2), zp = pack2(dinv*(e@W1^T + e^2@W2^T))
// Half-wave per node: lane q in [0,32) computes output dims 2q, 2q+1; dword stores.
__global__ __launch_bounds__(512, 8) void k_xform(
    const float2* __restrict__ embed2, const float* __restrict__ dinv,
    const float4* __restrict__ wBg, const float* __restrict__ b1,
    const float* __restrict__ b2, unsigned int* __restrict__ y1p,
    unsigned int* __restrict__ zp, int n) {
    __shared__ float4 wB[2048];        // [k*32+q]
    __shared__ float4 ebuf[8][2][32];  // [wave][half][q] = {e2q, e2q^2, e2q+1, e2q+1^2}
    int tid = threadIdx.x;
#pragma unroll
    for (int t = 0; t < 4; t++) wB[tid + 512 * t] = wBg[tid + 512 * t];
    __syncthreads();
    int wave = tid >> 6, lane = tid & 63, half = lane >> 5, q = lane & 31;
    float bs0 = b1[2 * q] + b2[2 * q];
    float bs1 = b1[2 * q + 1] + b2[2 * q + 1];
    for (int ip = blockIdx.x * 16 + wave * 2; ip < n; ip += gridDim.x * 16) {
        int i = ip + half;
        int ic = i < n ? i : n - 1;
        float2 ev = embed2[(size_t)ic * 32 + q];
        ebuf[wave][half][q] = make_float4(ev.x, ev.x * ev.x, ev.y, ev.y * ev.y);
        const float2* eb = (const float2*)&ebuf[wave][half][0];  // [k] = {e_k, e_k^2}
        float y0 = 0.f, s0 = 0.f, y1 = 0.f, s1 = 0.f;
#pragma unroll
        for (int k = 0; k < 64; k++) {
            float4 w = wB[(k << 5) + q];   // b128, consecutive lanes: conflict-free
            float2 ee = eb[k];             // uniform per half-wave: broadcast
            y0 = fmaf(ee.x, w.x, y0);
            s0 = fmaf(ee.y, w.y, s0);
            y1 = fmaf(ee.x, w.z, y1);
            s1 = fmaf(ee.y, w.w, s1);
        }
        if (i < n) {
            float di = dinv[i];
            y1p[(size_t)i * 32 + q] = f2bf(y0 + bs0) | (f2bf(y1 + bs1) << 16);
            zp[(size_t)i * 32 + q] = f2bf(di * (y0 + s0)) | (f2bf(di * (y1 + s1)) << 16);
        }
    }
}

// Pure gather-sum over ELL rows: 16-lane group per node, 4 nodes/wave.
__global__ __launch_bounds__(256, 8) void k_main(
    const ushort4* __restrict__ zb4, const ushort4* __restrict__ y1b4,
    const int* __restrict__ cursor, const int* __restrict__ scol,
    const float* __restrict__ dinv, float4* __restrict__ out4, int n) {
    int tid = threadIdx.x;
    int wave = tid >> 6, lane = tid & 63, g = lane >> 4, l = lane & 15;
    int i = blockIdx.x * 16 + wave * 4 + g;
    bool valid = i < n;
    int ii = valid ? i : 0;
    int s0 = ii * SLOTS;
    int deg = cursor[ii] - s0;
    deg = deg > SLOTS ? SLOTS : deg;
    int s1 = valid ? s0 + deg : s0;

    float4 acc = make_float4(0.f, 0.f, 0.f, 0.f);
    for (int e = s0; e < s1; e += 16) {
        int cnt = s1 - e;
        cnt = cnt > 16 ? 16 : cnt;
        int jv = scol[e + (l < cnt ? l : 0)];
#pragma unroll 8
        for (int k = 0; k < 16; k++) {
            int j = __shfl(jv, (g << 4) + k, 64);
            float m = (k < cnt) ? 1.0f : 0.0f;
            ushort4 z = zb4[(size_t)j * 16 + l];
            acc.x = fmaf(bf2f(z.x), m, acc.x);
            acc.y = fmaf(bf2f(z.y), m, acc.y);
            acc.z = fmaf(bf2f(z.z), m, acc.z);
            acc.w = fmaf(bf2f(z.w), m, acc.w);
        }
    }
    if (valid) {
        float di = dinv[i];
        ushort4 yb = y1b4[(size_t)i * 16 + l];
        float4 o;
        o.x = fmaf(di, acc.x, bf2f(yb.x));
        o.y = fmaf(di, acc.y, bf2f(yb.y));
        o.z = fmaf(di, acc.z, bf2f(yb.z));
        o.w = fmaf(di, acc.w, bf2f(yb.w));
        out4[(size_t)i * 16 + l] = o;
    }
}

extern "C" void kernel_launch(void* const* d_in, const int* in_sizes, int n_in,
                              void* d_out, int out_size, void* d_ws, size_t ws_size,
                              hipStream_t stream) {
    const float* embed = (const float*)d_in[0];
    const int* row = (const int*)d_in[1];
    const int* col = (const int*)d_in[2];
    const float* W1 = (const float*)d_in[3];
    const float* b1 = (const float*)d_in[4];
    const float* W2 = (const float*)d_in[5];
    const float* b2 = (const float*)d_in[6];
    float* out = (float*)d_out;

    int n = in_sizes[0] / 64;   // 144242
    int E = in_sizes[1];        // 2,000,000
    int Eh = E / 2;             // symmetric pairs: row=[u;it], col=[it;u]
    size_t n64 = (size_t)n * 64;
    int nS = n * SLOTS;

    char* ws = (char*)d_ws;
    size_t off = 0;
    unsigned int* zp = (unsigned int*)(ws + off);  off += n64 * 2;          // 18.5 MB
    unsigned int* y1p = (unsigned int*)(ws + off); off += n64 * 2;          // 18.5 MB
    float4* wBg = (float4*)(ws + off);             off += 2048 * 16;
    int* scol = (int*)(ws + off);                  off += ((size_t)nS + 16) * 4; // 27.7 MB
    int* posr = (int*)(ws + off);                  off += (size_t)Eh * 4;   // 4 MB
    int* posc = (int*)(ws + off);                  off += (size_t)Eh * 4;   // 4 MB
    int* cursor = (int*)(ws + off);                off += (size_t)n * 4;
    float* dinv = (float*)(ws + off);              off += (size_t)n * 4;

    if (off > ws_size) return;  // ws too small -> out stays zero (0.707 absmax signal)

    int pthreads = (Eh + 1) / 2;
    k_init<<<(n + 255) / 256, 256, 0, stream>>>(cursor, n);
    k_posA<<<(pthreads + 255) / 256, 256, 0, stream>>>(row, col, cursor, posr, posc,
                                                       Eh, nS);
    k_prep<<<(n + 255) / 256, 256, 0, stream>>>(cursor, dinv, W1, W2, wBg, n);
    k_xform<<<2048, 512, 0, stream>>>((const float2*)embed, dinv, wBg, b1, b2,
                                      y1p, zp, n);
    int sthreads = (Eh + 3) / 4;
    k_scatterB<<<(sthreads + 255) / 256, 256, 0, stream>>>(row, col, posr, posc,
                                                           scol, Eh);
    k_main<<<(n + 15) / 16, 256, 0, stream>>>((const ushort4*)zp, (const ushort4*)y1p,
                                              cursor, scol, dinv, (float4*)out, n);
}

// Round 8
// 152.203 us; speedup vs baseline: 2.4505x; 1.4639x over previous
//
#include <hip/hip_runtime.h>

// GNN layer (fp32 in/out):
//   out_i = (e_i@W1^T + b1 + b2) + dinv_i * sum_{j in N(i)} z_j
//   z_j   = dinv_j * (e_j@W1^T + e_j^2@W2^T)
// (refactor of: (e + L e)@W1^T + b1 + (L e^2)@W2^T + b2, L = D^-1/2 A D^-1/2)
// Symmetric edge layout row=[u;it], col=[it;u] -> one pass over 1M pairs.
// HW rules learned on this problem:
//  (r4) sub-dword global stores -> ECC RMW amplification. Pack to >=4B.
//  (r5) scattered 4B global stores write ~64B/line (cross-XCD line migration).
//  (r6) scattered global atomics are no better (same writeback physics).
//  (r7) scattered RETURNING atomics write ~32B/op straight to HBM (70MB for
//       2M ops on a 577KB counter array) -> ~0.85 TB/s effective. Eliminate.
// => This round: two-level LDS counting sort. All rank atomics are LDS-side;
//    all global stores are dense runs. Exact CSR, no drops.

#define NB 256          // blocks for count/scatter passes (must equal blockDim)
#define MAXBUCK 608     // LDS arrays sized for nbuck = ceil(n/256) = 564

__device__ __forceinline__ float bf2f(unsigned short u) {
    union { unsigned int i; float f; } c; c.i = ((unsigned int)u) << 16; return c.f;
}
__device__ __forceinline__ unsigned int f2bf(float f) {
    union { float f; unsigned int i; } c; c.f = f;
    unsigned int r = c.i + 0x7FFFu + ((c.i >> 16) & 1u);  // RTN-even
    return r >> 16;
}

// Pass 1: per-block histogram over coarse buckets (node>>8). LDS atomics only.
__global__ __launch_bounds__(256) void k1_count(const int* __restrict__ row,
                                                const int* __restrict__ col,
                                                int* __restrict__ H, int Eh, int nbuck) {
    __shared__ int hist[MAXBUCK];
    int tid = threadIdx.x, b = blockIdx.x;
    for (int i = tid; i < nbuck; i += 256) hist[i] = 0;
    __syncthreads();
    int chunk = (Eh + NB - 1) / NB;
    int e0 = b * chunk, e1 = min(e0 + chunk, Eh);
    for (int e = e0 + tid; e < e1; e += 256) {
        int u = row[e], v = col[e];
        atomicAdd(&hist[u >> 8], 1);
        atomicAdd(&hist[v >> 8], 1);
    }
    __syncthreads();
    for (int i = tid; i < nbuck; i += 256) H[b * nbuck + i] = hist[i];
}

// Pass 2a: per-bucket exclusive scan over the 256 blocks.
__global__ __launch_bounds__(256) void k2_colscan(const int* __restrict__ H,
                                                  int* __restrict__ Off,
                                                  int* __restrict__ btot, int nbuck) {
    __shared__ int lds[256];
    int t = threadIdx.x, beta = blockIdx.x;
    int v = H[t * nbuck + beta];
    lds[t] = v;
    __syncthreads();
    for (int off = 1; off < 256; off <<= 1) {
        int x = (t >= off) ? lds[t - off] : 0;
        __syncthreads();
        lds[t] += x;
        __syncthreads();
    }
    Off[beta * NB + t] = lds[t] - v;
    if (t == 255) btot[beta] = lds[255];
}

// Pass 2b: exclusive scan of bucket totals + weight-buffer prep + start[n].
// wBg[k*32+q] = {W1[2q][k], W2[2q][k], W1[2q+1][k], W2[2q+1][k]}
__global__ __launch_bounds__(1024) void k2b_bscan(const int* __restrict__ btot,
                                                  int* __restrict__ bbase, int nbuck, int E,
                                                  const float* __restrict__ W1,
                                                  const float* __restrict__ W2,
                                                  float4* __restrict__ wBg,
                                                  int* __restrict__ start, int n) {
    __shared__ int lds[1024];
    int t = threadIdx.x;
    int v = (t < nbuck) ? btot[t] : 0;
    lds[t] = v;
    __syncthreads();
    for (int off = 1; off < 1024; off <<= 1) {
        int x = (t >= off) ? lds[t - off] : 0;
        __syncthreads();
        lds[t] += x;
        __syncthreads();
    }
    if (t < nbuck) bbase[t] = lds[t] - v;
    if (t == nbuck) bbase[t] = E;
    if (t == 0) start[n] = E;
    for (int i = t; i < 2048; i += 1024) {
        int k = i >> 5, q = i & 31;
        wBg[i] = make_float4(W1[(2 * q) * 64 + k], W2[(2 * q) * 64 + k],
                             W1[(2 * q + 1) * 64 + k], W2[(2 * q + 1) * 64 + k]);
    }
}

// Pass 3: scatter (dest,src) records to coarse-bucket regions. Ranks from LDS
// cursors; global stores land in ~110B contiguous runs per (bucket,block).
__global__ __launch_bounds__(256) void k3_scatter(const int* __restrict__ row,
                                                  const int* __restrict__ col,
                                                  const int* __restrict__ Off,
                                                  const int* __restrict__ bbase,
                                                  int2* __restrict__ rec, int Eh, int nbuck) {
    __shared__ int cur[MAXBUCK];
    int tid = threadIdx.x, b = blockIdx.x;
    for (int i = tid; i < nbuck; i += 256) cur[i] = bbase[i] + Off[i * NB + b];
    __syncthreads();
    int chunk = (Eh + NB - 1) / NB;
    int e0 = b * chunk, e1 = min(e0 + chunk, Eh);
    for (int e = e0 + tid; e < e1; e += 256) {
        int u = row[e], v = col[e];
        int p = atomicAdd(&cur[u >> 8], 1);
        rec[p] = make_int2(u, v);
        int q = atomicAdd(&cur[v >> 8], 1);
        rec[q] = make_int2(v, u);
    }
}

// Pass 4: per-bucket (256 nodes) counting sort -> exact CSR start/dinv/scol.
__global__ __launch_bounds__(256) void k4_local(const int2* __restrict__ rec,
                                                const int* __restrict__ bbase,
                                                int* __restrict__ start,
                                                float* __restrict__ dinv,
                                                int* __restrict__ scol, int n) {
    __shared__ int hist[256], lcur[256], lds[256];
    int t = threadIdx.x, beta = blockIdx.x;
    int base = bbase[beta];
    int cnt = bbase[beta + 1] - base;
    hist[t] = 0;
    __syncthreads();
    for (int r = base + t; r < base + cnt; r += 256)
        atomicAdd(&hist[rec[r].x & 255], 1);
    __syncthreads();
    int h = hist[t];
    lds[t] = h;
    __syncthreads();
    for (int off = 1; off < 256; off <<= 1) {
        int x = (t >= off) ? lds[t - off] : 0;
        __syncthreads();
        lds[t] += x;
        __syncthreads();
    }
    int excl = lds[t] - h;
    int node = (beta << 8) + t;
    if (node < n) {
        start[node] = base + excl;
        dinv[node] = h > 0 ? rsqrtf((float)h) : 0.0f;
    }
    lcur[t] = base + excl;
    __syncthreads();
    for (int r = base + t; r < base + cnt; r += 256) {
        int2 rr = rec[r];
        int p = atomicAdd(&lcur[rr.x & 255], 1);
        scol[p] = rr.y;   // dense within the bucket's contiguous region
    }
}

// Per-node transform: y1p = pack2(e@W1^T + b1 + b2), zp = pack2(dinv*(e@W1^T + e^2@W2^T))
// Half-wave per node: lane q in [0,32) computes output dims 2q, 2q+1; dword stores.
__global__ __launch_bounds__(512, 8) void k_xform(
    const float2* __restrict__ embed2, const float* __restrict__ dinv,
    const float4* __restrict__ wBg, const float* __restrict__ b1,
    const float* __restrict__ b2, unsigned int* __restrict__ y1p,
    unsigned int* __restrict__ zp, int n) {
    __shared__ float4 wB[2048];        // [k*32+q]
    __shared__ float4 ebuf[8][2][32];  // [wave][half][q] = {e2q, e2q^2, e2q+1, e2q+1^2}
    int tid = threadIdx.x;
#pragma unroll
    for (int t = 0; t < 4; t++) wB[tid + 512 * t] = wBg[tid + 512 * t];
    __syncthreads();
    int wave = tid >> 6, lane = tid & 63, half = lane >> 5, q = lane & 31;
    float bs0 = b1[2 * q] + b2[2 * q];
    float bs1 = b1[2 * q + 1] + b2[2 * q + 1];
    for (int ip = blockIdx.x * 16 + wave * 2; ip < n; ip += gridDim.x * 16) {
        int i = ip + half;
        int ic = i < n ? i : n - 1;
        float2 ev = embed2[(size_t)ic * 32 + q];
        ebuf[wave][half][q] = make_float4(ev.x, ev.x * ev.x, ev.y, ev.y * ev.y);
        const float2* eb = (const float2*)&ebuf[wave][half][0];  // [k] = {e_k, e_k^2}
        float y0 = 0.f, s0 = 0.f, y1 = 0.f, s1 = 0.f;
#pragma unroll
        for (int k = 0; k < 64; k++) {
            float4 w = wB[(k << 5) + q];   // b128, consecutive lanes: conflict-free
            float2 ee = eb[k];             // uniform per half-wave: broadcast
            y0 = fmaf(ee.x, w.x, y0);
            s0 = fmaf(ee.y, w.y, s0);
            y1 = fmaf(ee.x, w.z, y1);
            s1 = fmaf(ee.y, w.w, s1);
        }
        if (i < n) {
            float di = dinv[i];
            y1p[(size_t)i * 32 + q] = f2bf(y0 + bs0) | (f2bf(y1 + bs1) << 16);
            zp[(size_t)i * 32 + q] = f2bf(di * (y0 + s0)) | (f2bf(di * (y1 + s1)) << 16);
        }
    }
}

// Pure gather-sum over CSR rows: 16-lane group per node, 4 nodes/wave.
__global__ __launch_bounds__(256, 8) void k_main(
    const ushort4* __restrict__ zb4, const ushort4* __restrict__ y1b4,
    const int* __restrict__ start, const int* __restrict__ scol,
    const float* __restrict__ dinv, float4* __restrict__ out4, int n) {
    int tid = threadIdx.x;
    int wave = tid >> 6, lane = tid & 63, g = lane >> 4, l = lane & 15;
    int i = blockIdx.x * 16 + wave * 4 + g;
    bool valid = i < n;
    int ii = valid ? i : 0;
    int s0 = start[ii];
    int s1 = valid ? start[ii + 1] : s0;

    float4 acc = make_float4(0.f, 0.f, 0.f, 0.f);
    for (int e = s0; e < s1; e += 16) {
        int cnt = s1 - e;
        cnt = cnt > 16 ? 16 : cnt;
        int jv = scol[e + (l < cnt ? l : 0)];
#pragma unroll 8
        for (int k = 0; k < 16; k++) {
            int j = __shfl(jv, (g << 4) + k, 64);
            float m = (k < cnt) ? 1.0f : 0.0f;
            ushort4 z = zb4[(size_t)j * 16 + l];
            acc.x = fmaf(bf2f(z.x), m, acc.x);
            acc.y = fmaf(bf2f(z.y), m, acc.y);
            acc.z = fmaf(bf2f(z.z), m, acc.z);
            acc.w = fmaf(bf2f(z.w), m, acc.w);
        }
    }
    if (valid) {
        float di = dinv[i];
        ushort4 yb = y1b4[(size_t)i * 16 + l];
        float4 o;
        o.x = fmaf(di, acc.x, bf2f(yb.x));
        o.y = fmaf(di, acc.y, bf2f(yb.y));
        o.z = fmaf(di, acc.z, bf2f(yb.z));
        o.w = fmaf(di, acc.w, bf2f(yb.w));
        out4[(size_t)i * 16 + l] = o;
    }
}

extern "C" void kernel_launch(void* const* d_in, const int* in_sizes, int n_in,
                              void* d_out, int out_size, void* d_ws, size_t ws_size,
                              hipStream_t stream) {
    const float* embed = (const float*)d_in[0];
    const int* row = (const int*)d_in[1];
    const int* col = (const int*)d_in[2];
    const float* W1 = (const float*)d_in[3];
    const float* b1 = (const float*)d_in[4];
    const float* W2 = (const float*)d_in[5];
    const float* b2 = (const float*)d_in[6];
    float* out = (float*)d_out;

    int n = in_sizes[0] / 64;   // 144242
    int E = in_sizes[1];        // 2,000,000
    int Eh = E / 2;             // symmetric pairs: row=[u;it], col=[it;u]
    int nbuck = (n + 255) >> 8; // 564
    size_t n64 = (size_t)n * 64;
    if (nbuck > MAXBUCK) return;  // fixed-size LDS guard

    char* ws = (char*)d_ws;
    size_t off = 0;
    unsigned int* zp = (unsigned int*)(ws + off);  off += n64 * 2;        // 18.5 MB
    unsigned int* y1p = (unsigned int*)(ws + off); off += n64 * 2;        // 18.5 MB
    float4* wBg = (float4*)(ws + off);             off += 2048 * 16;
    int2* rec = (int2*)(ws + off);                 off += (size_t)E * 8;  // 16 MB
    int* scol = (int*)(ws + off);                  off += (size_t)E * 4;  // 8 MB
    int* H = (int*)(ws + off);                     off += (size_t)NB * nbuck * 4;
    int* Off = (int*)(ws + off);                   off += (size_t)nbuck * NB * 4;
    int* btot = (int*)(ws + off);                  off += (size_t)nbuck * 4;
    int* bbase = (int*)(ws + off);                 off += (size_t)(nbuck + 1) * 4;
    int* start = (int*)(ws + off);                 off += (size_t)(n + 1) * 4;
    float* dinv = (float*)(ws + off);              off += (size_t)n * 4;

    if (off > ws_size) return;  // ws too small -> out stays zero (0.707 absmax signal)

    k1_count<<<NB, 256, 0, stream>>>(row, col, H, Eh, nbuck);
    k2_colscan<<<nbuck, 256, 0, stream>>>(H, Off, btot, nbuck);
    k2b_bscan<<<1, 1024, 0, stream>>>(btot, bbase, nbuck, E, W1, W2, wBg, start, n);
    k3_scatter<<<NB, 256, 0, stream>>>(row, col, Off, bbase, rec, Eh, nbuck);
    k4_local<<<nbuck, 256, 0, stream>>>(rec, bbase, start, dinv, scol, n);
    k_xform<<<2048, 512, 0, stream>>>((const float2*)embed, dinv, wBg, b1, b2,
                                      y1p, zp, n);
    k_main<<<(n + 15) / 16, 256, 0, stream>>>((const ushort4*)zp, (const ushort4*)y1p,
                                              start, scol, dinv, (float4*)out, n);
}

// Round 9
// 102.838 us; speedup vs baseline: 3.6267x; 1.4800x over previous
//
#include <hip/hip_runtime.h>

// GNN layer (fp32 in/out):
//   out_i = (e_i@W1^T + b1 + b2) + dinv_i * sum_{j in N(i)} z_j
//   z_j   = dinv_j * (e_j@W1^T + e_j^2@W2^T)
// (refactor of: (e + L e)@W1^T + b1 + (L e^2)@W2^T + b2, L = D^-1/2 A D^-1/2)
// Pipeline: two-level LDS counting sort -> exact CSR (r8, all rank atomics in
// LDS, all global stores dense), MFMA transform (this round), gather-sum.
// HW rules learned on this problem:
//  (r4) sub-dword global stores -> ECC RMW amplification. Pack to >=4B.
//  (r5) scattered 4B stores write ~64B/line (cross-XCD migration).
//  (r6) scattered global atomics: same writeback physics.
//  (r7) scattered RETURNING atomics: ~32B/op write-through to HBM.
//  (r8) dense [n,64]@[64,64] on VALU is LDS-issue-bound (65% VALUBusy,
//       5x over FMA roofline) -> MFMA (G10).
// Table packing: dword q of zp/y1p holds bf16 dims (q, q+32)  [MFMA-epilogue
// native]. k_main stores out as two float2 per lane accordingly.

#define NB 256          // blocks for count/scatter passes (must equal blockDim)
#define MAXBUCK 608     // LDS arrays sized for nbuck = ceil(n/256) = 564

typedef short bf16x8 __attribute__((ext_vector_type(8)));
typedef float f32x4 __attribute__((ext_vector_type(4)));

__device__ __forceinline__ float bf2f(unsigned short u) {
    union { unsigned int i; float f; } c; c.i = ((unsigned int)u) << 16; return c.f;
}
__device__ __forceinline__ unsigned int f2bf(float f) {
    union { float f; unsigned int i; } c; c.f = f;
    unsigned int r = c.i + 0x7FFFu + ((c.i >> 16) & 1u);  // RTN-even
    return r >> 16;
}
__device__ __forceinline__ unsigned int pk2(float a, float b) {
    return f2bf(a) | (f2bf(b) << 16);
}

// ---------------- CSR build: two-level LDS counting sort (r8) ----------------

__global__ __launch_bounds__(256) void k1_count(const int* __restrict__ row,
                                                const int* __restrict__ col,
                                                int* __restrict__ H, int Eh, int nbuck) {
    __shared__ int hist[MAXBUCK];
    int tid = threadIdx.x, b = blockIdx.x;
    for (int i = tid; i < nbuck; i += 256) hist[i] = 0;
    __syncthreads();
    int chunk = (Eh + NB - 1) / NB;
    int e0 = b * chunk, e1 = min(e0 + chunk, Eh);
    for (int e = e0 + tid; e < e1; e += 256) {
        int u = row[e], v = col[e];
        atomicAdd(&hist[u >> 8], 1);
        atomicAdd(&hist[v >> 8], 1);
    }
    __syncthreads();
    for (int i = tid; i < nbuck; i += 256) H[b * nbuck + i] = hist[i];
}

__global__ __launch_bounds__(256) void k2_colscan(const int* __restrict__ H,
                                                  int* __restrict__ Off,
                                                  int* __restrict__ btot, int nbuck) {
    __shared__ int lds[256];
    int t = threadIdx.x, beta = blockIdx.x;
    int v = H[t * nbuck + beta];
    lds[t] = v;
    __syncthreads();
    for (int off = 1; off < 256; off <<= 1) {
        int x = (t >= off) ? lds[t - off] : 0;
        __syncthreads();
        lds[t] += x;
        __syncthreads();
    }
    Off[beta * NB + t] = lds[t] - v;
    if (t == 255) btot[beta] = lds[255];
}

__global__ __launch_bounds__(1024) void k2b_bscan(const int* __restrict__ btot,
                                                  int* __restrict__ bbase, int nbuck,
                                                  int E, int* __restrict__ start, int n) {
    __shared__ int lds[1024];
    int t = threadIdx.x;
    int v = (t < nbuck) ? btot[t] : 0;
    lds[t] = v;
    __syncthreads();
    for (int off = 1; off < 1024; off <<= 1) {
        int x = (t >= off) ? lds[t - off] : 0;
        __syncthreads();
        lds[t] += x;
        __syncthreads();
    }
    if (t < nbuck) bbase[t] = lds[t] - v;
    if (t == nbuck) bbase[t] = E;
    if (t == 0) start[n] = E;
}

__global__ __launch_bounds__(256) void k3_scatter(const int* __restrict__ row,
                                                  const int* __restrict__ col,
                                                  const int* __restrict__ Off,
                                                  const int* __restrict__ bbase,
                                                  int2* __restrict__ rec, int Eh, int nbuck) {
    __shared__ int cur[MAXBUCK];
    int tid = threadIdx.x, b = blockIdx.x;
    for (int i = tid; i < nbuck; i += 256) cur[i] = bbase[i] + Off[i * NB + b];
    __syncthreads();
    int chunk = (Eh + NB - 1) / NB;
    int e0 = b * chunk, e1 = min(e0 + chunk, Eh);
    for (int e = e0 + tid; e < e1; e += 256) {
        int u = row[e], v = col[e];
        int p = atomicAdd(&cur[u >> 8], 1);
        rec[p] = make_int2(u, v);
        int q = atomicAdd(&cur[v >> 8], 1);
        rec[q] = make_int2(v, u);
    }
}

__global__ __launch_bounds__(256) void k4_local(const int2* __restrict__ rec,
                                                const int* __restrict__ bbase,
                                                int* __restrict__ start,
                                                float* __restrict__ dinv,
                                                int* __restrict__ scol, int n) {
    __shared__ int hist[256], lcur[256], lds[256];
    int t = threadIdx.x, beta = blockIdx.x;
    int base = bbase[beta];
    int cnt = bbase[beta + 1] - base;
    hist[t] = 0;
    __syncthreads();
    for (int r = base + t; r < base + cnt; r += 256)
        atomicAdd(&hist[rec[r].x & 255], 1);
    __syncthreads();
    int h = hist[t];
    lds[t] = h;
    __syncthreads();
    for (int off = 1; off < 256; off <<= 1) {
        int x = (t >= off) ? lds[t - off] : 0;
        __syncthreads();
        lds[t] += x;
        __syncthreads();
    }
    int excl = lds[t] - h;
    int node = (beta << 8) + t;
    if (node < n) {
        start[node] = base + excl;
        dinv[node] = h > 0 ? rsqrtf((float)h) : 0.0f;
    }
    lcur[t] = base + excl;
    __syncthreads();
    for (int r = base + t; r < base + cnt; r += 256) {
        int2 rr = rec[r];
        int p = atomicAdd(&lcur[rr.x & 255], 1);
        scol[p] = rr.y;
    }
}

// ---------------- MFMA transform (r9) ----------------
// Per block: 4 waves x 16-node tiles. Y = E@W1^T, S = E2@W2^T via
// mfma_f32_16x16x32_bf16 (bt-GEMM fragment pattern, K=64 -> 2 frags).
// LDS bf16 tiles XOR-swizzled (dw ^= (row&7)<<2) -> <=2-way conflicts.
// Epilogue packs dword q = dims (q, q+32): tile t pairs with tile t+2 in-lane.
__global__ __launch_bounds__(256) void k_xform(
    const float4* __restrict__ embed4, const float* __restrict__ dinv,
    const float4* __restrict__ W1_4, const float4* __restrict__ W2_4,
    const float* __restrict__ b1, const float* __restrict__ b2,
    unsigned int* __restrict__ y1p, unsigned int* __restrict__ zp, int n) {
    __shared__ __align__(16) unsigned int lW[2][2048];     // [mat][row*32+dw] 64x64 bf16
    __shared__ __align__(16) unsigned int lA[4][2][512];   // [wave][e|e2][row*32+dw] 16x64

    int tid = threadIdx.x;
    int wave = tid >> 6, lane = tid & 63;
    int L = lane & 15, hi = lane >> 4;

    // stage W1/W2 -> bf16 LDS (coalesced read, swizzled write)
#pragma unroll
    for (int p = 0; p < 8; p++) {
        int idx = p * 256 + tid;              // 0..2047
        int mat = idx >> 10, rem = idx & 1023;
        int row = rem >> 4, col4 = rem & 15;
        float4 v = (mat ? W2_4 : W1_4)[rem];
        int dw = (row * 32 + col4 * 2) ^ ((row & 7) << 2);
        *(int2*)&lW[mat][dw] = make_int2(pk2(v.x, v.y), pk2(v.z, v.w));
    }
    __syncthreads();

    // B fragments (held in VGPRs): [mat][tile][kfrag]
    bf16x8 bfr[2][4][2];
#pragma unroll
    for (int m = 0; m < 2; m++)
#pragma unroll
        for (int t = 0; t < 4; t++)
#pragma unroll
            for (int kf = 0; kf < 2; kf++) {
                int row = 16 * t + L;
                int dw = (row * 32 + kf * 16 + hi * 4) ^ ((L & 7) << 2);
                int4 raw = *(const int4*)&lW[m][dw];
                bfr[m][t][kf] = *(bf16x8*)&raw;
            }

    // stage this wave's 16-node e / e^2 tile
    int tb16 = blockIdx.x * 64 + wave * 16;
#pragma unroll
    for (int p = 0; p < 4; p++) {
        int idx = p * 64 + lane;              // 0..255
        int row = idx >> 4, col4 = idx & 15;
        int node = tb16 + row;
        int nc = node < n ? node : n - 1;
        float4 v = embed4[(size_t)nc * 16 + col4];
        int dw = (row * 32 + col4 * 2) ^ ((row & 7) << 2);
        *(int2*)&lA[wave][0][dw] = make_int2(pk2(v.x, v.y), pk2(v.z, v.w));
        *(int2*)&lA[wave][1][dw] = make_int2(pk2(v.x * v.x, v.y * v.y),
                                             pk2(v.z * v.z, v.w * v.w));
    }
    // wave-local LDS write->read: compiler-inserted lgkmcnt orders it.

    f32x4 accY[4], accS[4];
#pragma unroll
    for (int t = 0; t < 4; t++) { accY[t] = (f32x4)0.f; accS[t] = (f32x4)0.f; }
#pragma unroll
    for (int kf = 0; kf < 2; kf++) {
        int dw = (L * 32 + kf * 16 + hi * 4) ^ ((L & 7) << 2);
        int4 rawE = *(const int4*)&lA[wave][0][dw];
        int4 rawQ = *(const int4*)&lA[wave][1][dw];
        bf16x8 aE = *(bf16x8*)&rawE;
        bf16x8 aQ = *(bf16x8*)&rawQ;
#pragma unroll
        for (int t = 0; t < 4; t++) {
            accY[t] = __builtin_amdgcn_mfma_f32_16x16x32_bf16(aE, bfr[0][t][kf], accY[t], 0, 0, 0);
            accS[t] = __builtin_amdgcn_mfma_f32_16x16x32_bf16(aQ, bfr[1][t][kf], accS[t], 0, 0, 0);
        }
    }

    // epilogue: C[row=4*hi+r][col=16t+L]; dword q=(16*{0,1})+L holds dims (q,q+32)
    float bs0 = b1[L] + b2[L];
    float bs1 = b1[16 + L] + b2[16 + L];
    float bs2 = b1[32 + L] + b2[32 + L];
    float bs3 = b1[48 + L] + b2[48 + L];
#pragma unroll
    for (int r = 0; r < 4; r++) {
        int node = tb16 + 4 * hi + r;
        if (node >= n) continue;
        float di = dinv[node];
        float y0 = accY[0][r], y1 = accY[1][r], y2 = accY[2][r], y3 = accY[3][r];
        float s0 = accS[0][r], s1 = accS[1][r], s2 = accS[2][r], s3 = accS[3][r];
        size_t base = (size_t)node * 32;
        y1p[base + L]      = pk2(y0 + bs0, y2 + bs2);
        y1p[base + 16 + L] = pk2(y1 + bs1, y3 + bs3);
        zp[base + L]       = pk2(di * (y0 + s0), di * (y2 + s2));
        zp[base + 16 + L]  = pk2(di * (y1 + s1), di * (y3 + s3));
    }
}

// ---------------- gather-sum ----------------
// 16-lane group per node, 4 nodes/wave. Table dword q = dims (q, q+32), so
// lane l accumulates dims (2l, 2l+32, 2l+1, 2l+33) and stores two float2.
__global__ __launch_bounds__(256, 8) void k_main(
    const ushort4* __restrict__ zb4, const ushort4* __restrict__ y1b4,
    const int* __restrict__ start, const int* __restrict__ scol,
    const float* __restrict__ dinv, float2* __restrict__ out2, int n) {
    int tid = threadIdx.x;
    int wave = tid >> 6, lane = tid & 63, g = lane >> 4, l = lane & 15;
    int i = blockIdx.x * 16 + wave * 4 + g;
    bool valid = i < n;
    int ii = valid ? i : 0;
    int s0 = start[ii];
    int s1 = valid ? start[ii + 1] : s0;

    float4 acc = make_float4(0.f, 0.f, 0.f, 0.f);
    for (int e = s0; e < s1; e += 16) {
        int cnt = s1 - e;
        cnt = cnt > 16 ? 16 : cnt;
        int jv = scol[e + (l < cnt ? l : 0)];
#pragma unroll 8
        for (int k = 0; k < 16; k++) {
            int j = __shfl(jv, (g << 4) + k, 64);
            float m = (k < cnt) ? 1.0f : 0.0f;
            ushort4 z = zb4[(size_t)j * 16 + l];
            acc.x = fmaf(bf2f(z.x), m, acc.x);
            acc.y = fmaf(bf2f(z.y), m, acc.y);
            acc.z = fmaf(bf2f(z.z), m, acc.z);
            acc.w = fmaf(bf2f(z.w), m, acc.w);
        }
    }
    if (valid) {
        float di = dinv[i];
        ushort4 yb = y1b4[(size_t)i * 16 + l];
        float4 o;
        o.x = fmaf(di, acc.x, bf2f(yb.x));   // dim 2l
        o.y = fmaf(di, acc.y, bf2f(yb.y));   // dim 2l+32
        o.z = fmaf(di, acc.z, bf2f(yb.z));   // dim 2l+1
        o.w = fmaf(di, acc.w, bf2f(yb.w));   // dim 2l+33
        out2[(size_t)i * 32 + l] = make_float2(o.x, o.z);
        out2[(size_t)i * 32 + 16 + l] = make_float2(o.y, o.w);
    }
}

extern "C" void kernel_launch(void* const* d_in, const int* in_sizes, int n_in,
                              void* d_out, int out_size, void* d_ws, size_t ws_size,
                              hipStream_t stream) {
    const float* embed = (const float*)d_in[0];
    const int* row = (const int*)d_in[1];
    const int* col = (const int*)d_in[2];
    const float* W1 = (const float*)d_in[3];
    const float* b1 = (const float*)d_in[4];
    const float* W2 = (const float*)d_in[5];
    const float* b2 = (const float*)d_in[6];
    float* out = (float*)d_out;

    int n = in_sizes[0] / 64;   // 144242
    int E = in_sizes[1];        // 2,000,000
    int Eh = E / 2;             // symmetric pairs: row=[u;it], col=[it;u]
    int nbuck = (n + 255) >> 8; // 564
    size_t n64 = (size_t)n * 64;
    if (nbuck > MAXBUCK) return;  // fixed-size LDS guard

    char* ws = (char*)d_ws;
    size_t off = 0;
    unsigned int* zp = (unsigned int*)(ws + off);  off += n64 * 2;        // 18.5 MB
    unsigned int* y1p = (unsigned int*)(ws + off); off += n64 * 2;        // 18.5 MB
    int2* rec = (int2*)(ws + off);                 off += (size_t)E * 8;  // 16 MB
    int* scol = (int*)(ws + off);                  off += (size_t)E * 4;  // 8 MB
    int* H = (int*)(ws + off);                     off += (size_t)NB * nbuck * 4;
    int* Off = (int*)(ws + off);                   off += (size_t)nbuck * NB * 4;
    int* btot = (int*)(ws + off);                  off += (size_t)nbuck * 4;
    int* bbase = (int*)(ws + off);                 off += (size_t)(nbuck + 1) * 4;
    int* start = (int*)(ws + off);                 off += (size_t)(n + 1) * 4;
    float* dinv = (float*)(ws + off);              off += (size_t)n * 4;

    if (off > ws_size) return;  // ws too small -> out stays zero (0.707 absmax signal)

    k1_count<<<NB, 256, 0, stream>>>(row, col, H, Eh, nbuck);
    k2_colscan<<<nbuck, 256, 0, stream>>>(H, Off, btot, nbuck);
    k2b_bscan<<<1, 1024, 0, stream>>>(btot, bbase, nbuck, E, start, n);
    k3_scatter<<<NB, 256, 0, stream>>>(row, col, Off, bbase, rec, Eh, nbuck);
    k4_local<<<nbuck, 256, 0, stream>>>(rec, bbase, start, dinv, scol, n);
    k_xform<<<(n + 63) / 64, 256, 0, stream>>>((const float4*)embed, dinv,
                                               (const float4*)W1, (const float4*)W2,
                                               b1, b2, y1p, zp, n);
    k_main<<<(n + 15) / 16, 256, 0, stream>>>((const ushort4*)zp, (const ushort4*)y1p,
                                              start, scol, dinv, (float2*)out, n);
}